// Round 14
// baseline (87.846 us; speedup 1.0000x reference)
//
#include <hip/hip_runtime.h>
#include <hip/hip_bf16.h>

#define NB 32768      // batch rows per node
#define CD 128        // input channels
#define NNODES 6
#define OUTW 1536     // 6*256 output cols
#define KW 256        // concat K per node GEMM
#define GPB 4         // row-groups per block
#define NBLK (NB / 16 / GPB)   // 512 blocks = 2 per CU (LDS 80KB each)

typedef __attribute__((ext_vector_type(8))) short short8;
typedef __attribute__((ext_vector_type(4))) short s16x4;   // 'short4' is a HIP builtin
typedef __attribute__((ext_vector_type(4))) float f32x4;

// hardware f32->bf16 (RNE)
static __device__ __forceinline__ short f2bf(float f) {
    union { __bf16 b; short s; } u;
    u.b = (__bf16)f;
    return u.s;
}

static __device__ __forceinline__ short8 pack8(f32x4 a, f32x4 b) {
    short8 p;
    #pragma unroll
    for (int j = 0; j < 4; ++j) { p[j] = f2bf(a[j]); p[4 + j] = f2bf(b[j]); }
    return p;
}

static __device__ __forceinline__ s16x4 pack4(f32x4 a) {
    s16x4 p;
    #pragma unroll
    for (int j = 0; j < 4; ++j) p[j] = f2bf(a[j]);
    return p;
}

// ---- prologue: Wcat[o][k] bf16 in d_ws; k<128 -> Wl[o][k], else Wr[o][k-128]
__global__ void prep_w(const float* __restrict__ Wl, const float* __restrict__ Wr,
                       short* __restrict__ Wb) {
    const int i = (blockIdx.x * 256 + threadIdx.x) * 8;
    const int o = i >> 8;
    const int k = i & 255;
    const float* src = (k < 128) ? (Wl + o * CD + k) : (Wr + o * CD + (k - 128));
    *(short8*)(Wb + i) = pack8(*(const f32x4*)src, *(const f32x4*)(src + 4));
}

// LDS short-index, XOR swizzle (byte ^= (r&7)<<4): panel p(0..9), row r(0..15),
// k(0..127). Bijective for 8B/16B accesses; reads 2-way max. Verified R5-R13.
// Panels: 0:g0 1:g1 2:g25 3:g34 4..9:x0..x5
#define LIDX(p, r, k) ((((p) << 11) + ((r) << 7) + (k)) ^ (((r) & 7) << 3))

// R14: 2 blocks/CU (A-dbuf 80KB only, raw-DMA staging dropped) so one
// block's MFMA/stores cover the other's convert/barrier gaps (R13 showed
// stores sustain 2.35 of 7 TB/s because 1 lockstep block/CU leaves the
// store pipe idle at every barrier). ONE barrier/iter: iter reads A[it&1],
// converts next group into A[(it+1)&1] (disjoint). Pair3 acc held in regs
// across the barrier, stored at next iter's start -> every store gets a
// full MFMA phase to drain. xv only live in the convert tail (no R9/R12
// spill pattern).
__global__ __launch_bounds__(512, 2)
void sage_v12(const float* __restrict__ x, const short* __restrict__ Wb,
              const float* __restrict__ bias, float* __restrict__ out) {
    __shared__ __align__(16) short A[2][10 * 16 * 128];   // 2 x 40 KB

    const int t = threadIdx.x;
    const int r = t >> 5;          // convert row 0..15
    const int c = t & 31;          // 4-float chunk 0..31
    const int lane = t & 63;
    const int wv = t >> 6;         // wave 0..7
    const int lo = lane & 15;
    const int hi = lane >> 4;
    const int obase = wv * 32;     // 32-col strip per wave (R10-validated)
    const size_t rg0 = (size_t)blockIdx.x * GPB;

    f32x4 bias4[2];
    #pragma unroll
    for (int i = 0; i < 2; ++i)
        bias4[i] = *(const f32x4*)&bias[obase + i * 16 + hi * 4];

    // ---- load x (transient) + convert into panels of Ad
    auto loadConvert = [&](short* __restrict__ Ad, size_t rg) {
        const float* pb = x + (rg * 16 + r) * CD + c * 4;
        f32x4 v0 = *(const f32x4*)(pb + 0ull * (NB * CD));
        f32x4 v1 = *(const f32x4*)(pb + 1ull * (NB * CD));
        f32x4 v2 = *(const f32x4*)(pb + 2ull * (NB * CD));
        f32x4 v3 = *(const f32x4*)(pb + 3ull * (NB * CD));
        f32x4 v4 = *(const f32x4*)(pb + 4ull * (NB * CD));
        f32x4 v5 = *(const f32x4*)(pb + 5ull * (NB * CD));
        f32x4 S01 = v0 + v1, S25 = v2 + v5, S34 = v3 + v4;
        f32x4 T = S01 + S25 + S34;
        const int k = c * 4;
        *(s16x4*)&Ad[LIDX(0, r, k)] = pack4((T - v0) * 0.2f);      // g0
        *(s16x4*)&Ad[LIDX(1, r, k)] = pack4((T - v1) * 0.2f);      // g1
        *(s16x4*)&Ad[LIDX(2, r, k)] = pack4((S01 + S34) * 0.25f);  // g25
        *(s16x4*)&Ad[LIDX(3, r, k)] = pack4((S01 + S25) * 0.25f);  // g34
        *(s16x4*)&Ad[LIDX(4, r, k)] = pack4(v0);
        *(s16x4*)&Ad[LIDX(5, r, k)] = pack4(v1);
        *(s16x4*)&Ad[LIDX(6, r, k)] = pack4(v2);
        *(s16x4*)&Ad[LIDX(7, r, k)] = pack4(v3);
        *(s16x4*)&Ad[LIDX(8, r, k)] = pack4(v4);
        *(s16x4*)&Ad[LIDX(9, r, k)] = pack4(v5);
    };

    // ---- one node-pair's MFMA accumulation (R13-validated)
    auto pairMFMA = [&](const short* __restrict__ Ab, int pa0, int pa1,
                        int px0, int px1, f32x4 acc[2][2]) {
        #pragma unroll
        for (int n = 0; n < 2; ++n)
            #pragma unroll
            for (int i = 0; i < 2; ++i) acc[n][i] = (f32x4){0.f, 0.f, 0.f, 0.f};
        #pragma unroll
        for (int m = 0; m < 4; ++m) {
            const int kk = m * 32 + hi * 8;
            short8 fa0 = *(const short8*)&Ab[LIDX(pa0, lo, kk)];
            short8 fa1 = *(const short8*)&Ab[LIDX(pa1, lo, kk)];
            short8 fx0 = *(const short8*)&Ab[LIDX(px0, lo, kk)];
            short8 fx1 = *(const short8*)&Ab[LIDX(px1, lo, kk)];
            #pragma unroll
            for (int i = 0; i < 2; ++i) {
                const int o = obase + i * 16 + lo;
                short8 wa = *(const short8*)&Wb[o * KW + kk];          // Wl half
                short8 wx = *(const short8*)&Wb[o * KW + 128 + kk];    // Wr half
                acc[0][i] = __builtin_amdgcn_mfma_f32_16x16x32_bf16(wa, fa0, acc[0][i], 0, 0, 0);
                acc[1][i] = __builtin_amdgcn_mfma_f32_16x16x32_bf16(wa, fa1, acc[1][i], 0, 0, 0);
                acc[0][i] = __builtin_amdgcn_mfma_f32_16x16x32_bf16(wx, fx0, acc[0][i], 0, 0, 0);
                acc[1][i] = __builtin_amdgcn_mfma_f32_16x16x32_bf16(wx, fx1, acc[1][i], 0, 0, 0);
            }
        }
    };

    // ---- GELU + stores for one node pair
    auto storePair = [&](int n0, int n1, f32x4 acc[2][2], size_t orow) {
        #pragma unroll
        for (int w = 0; w < 2; ++w) {
            const int node = w ? n1 : n0;
            #pragma unroll
            for (int i = 0; i < 2; ++i) {
                const int ocol = obase + i * 16 + hi * 4;
                f32x4 v = acc[w][i] + bias4[i];
                f32x4 g;
                #pragma unroll
                for (int j = 0; j < 4; ++j) {
                    const float s = v[j] * (0.7978845608f + 0.0356774081f * v[j] * v[j]);
                    const float rr = __builtin_amdgcn_exp2f(-2.885390082f * s);
                    g[j] = v[j] * __builtin_amdgcn_rcpf(1.0f + rr);
                }
                *(f32x4*)&out[orow * OUTW + node * 256 + ocol] = g;
            }
        }
    };

    // prologue: group 0 -> A[0]
    loadConvert(&A[0][0], rg0);
    __syncthreads();

    f32x4 accH[2][2];              // pair (3,4) held across barrier
    size_t prevRow = 0;

    #pragma unroll 1
    for (int it = 0; it < GPB; ++it) {
        if (it) __syncthreads();   // A[it&1] written by last iter's convert
        const short* Ab = &A[it & 1][0];
        const size_t orow = (rg0 + it) * 16 + lo;

        // prev group's pair3 stores: issued at phase start -> full phase to drain
        if (it) storePair(3, 4, accH, prevRow);

        f32x4 acc[2][2];
        pairMFMA(Ab, 0, 1, 4, 5, acc);   // nodes 0,1 (g0,g1)
        storePair(0, 1, acc, orow);
        pairMFMA(Ab, 2, 2, 6, 9, acc);   // nodes 2,5 (shared g25)
        storePair(2, 5, acc, orow);
        pairMFMA(Ab, 3, 3, 7, 8, accH);  // nodes 3,4 (shared g34) -> held
        prevRow = orow;

        // convert next group into the other buffer (xv transient; disjoint
        // from all concurrent MFMA reads of A[it&1] -> one barrier suffices)
        if (it + 1 < GPB) loadConvert(&A[(it + 1) & 1][0], rg0 + it + 1);
    }
    storePair(3, 4, accH, prevRow);      // final held pair; flushes at kernel end
}

extern "C" void kernel_launch(void* const* d_in, const int* in_sizes, int n_in,
                              void* d_out, int out_size, void* d_ws, size_t ws_size,
                              hipStream_t stream) {
    const float* x  = (const float*)d_in[0];
    const float* Wl = (const float*)d_in[1];
    const float* Wr = (const float*)d_in[2];
    const float* b  = (const float*)d_in[3];
    float* out = (float*)d_out;
    short* Wb = (short*)d_ws;   // 256*256 bf16 = 128 KB

    prep_w<<<dim3(32), dim3(256), 0, stream>>>(Wl, Wr, Wb);
    sage_v12<<<dim3(NBLK), dim3(512), 0, stream>>>(x, Wb, b, out);
}

// Round 15
// 86.960 us; speedup vs baseline: 1.0102x; 1.0102x over previous
//
#include <hip/hip_runtime.h>
#include <hip/hip_bf16.h>

#define NB 32768      // batch rows per node
#define CD 128        // input channels
#define NNODES 6
#define OUTW 1536     // 6*256 output cols
#define KW 256        // concat K per node GEMM
#define GPB 8         // row-groups per persistent block
#define NBLK (NB / 16 / GPB)   // 256 blocks = 1 per CU

typedef __attribute__((ext_vector_type(8))) short short8;
typedef __attribute__((ext_vector_type(4))) short s16x4;   // 'short4' is a HIP builtin
typedef __attribute__((ext_vector_type(4))) float f32x4;

// hardware f32->bf16 (RNE)
static __device__ __forceinline__ short f2bf(float f) {
    union { __bf16 b; short s; } u;
    u.b = (__bf16)f;
    return u.s;
}

static __device__ __forceinline__ short8 pack8(f32x4 a, f32x4 b) {
    short8 p;
    #pragma unroll
    for (int j = 0; j < 4; ++j) { p[j] = f2bf(a[j]); p[4 + j] = f2bf(b[j]); }
    return p;
}

static __device__ __forceinline__ s16x4 pack4(f32x4 a) {
    s16x4 p;
    #pragma unroll
    for (int j = 0; j < 4; ++j) p[j] = f2bf(a[j]);
    return p;
}

// ---- prologue: Wcat[o][k] bf16 in d_ws; k<128 -> Wl[o][k], else Wr[o][k-128]
__global__ void prep_w(const float* __restrict__ Wl, const float* __restrict__ Wr,
                       short* __restrict__ Wb) {
    const int i = (blockIdx.x * 256 + threadIdx.x) * 8;
    const int o = i >> 8;
    const int k = i & 255;
    const float* src = (k < 128) ? (Wl + o * CD + k) : (Wr + o * CD + (k - 128));
    *(short8*)(Wb + i) = pack8(*(const f32x4*)src, *(const f32x4*)(src + 4));
}

// LDS short-index, XOR swizzle (byte ^= (r&7)<<4): panel p(0..9), row r(0..15),
// k(0..127). Bijective for 8B/16B accesses; reads 2-way max. Verified R5-R14.
// Panels: 0:g0 1:g1 2:g25 3:g34 4..9:x0..x5
#define LIDX(p, r, k) ((((p) << 11) + ((r) << 7) + (k)) ^ (((r) & 7) << 3))

// R15 = R13's DMA pipeline +
//  (1) W fragments hoisted to registers (64 VGPR): LDS is 128KB -> 1 block/CU
//      -> 2 waves/SIMD -> 256-VGPR budget; launch_bounds(512,1) unlocks it.
//      Kills the 3x/iter W re-read (786 MB L2 traffic in R13).
//  (2) ONE barrier/iter: A panels double-buffered; raw DMA buffer SINGLE --
//      each wave converts exactly the raw region it DMA'd, so the DMA wait
//      is a per-wave asm vmcnt(0), not a barrier. Cross-wave A publication
//      happens at the single end-of-iter barrier.
//  (3) pair3 stores held in regs across the barrier (R14 trick): every
//      store gets >=1/3 MFMA phase + convert to drain before any vmcnt(0).
__global__ __launch_bounds__(512, 1)
void sage_v13(const float* __restrict__ x, const short* __restrict__ Wb,
              const float* __restrict__ bias, float* __restrict__ out) {
    __shared__ __align__(16) float raw[NNODES * 16 * 128];   // 48 KB, single
    __shared__ __align__(16) short A[2][10 * 16 * 128];      // 2 x 40 KB

    const int t = threadIdx.x;
    const int r = t >> 5;          // staging/convert row 0..15
    const int c = t & 31;          // 4-float chunk 0..31
    const int lane = t & 63;
    const int wv = t >> 6;         // wave 0..7
    const int lo = lane & 15;
    const int hi = lane >> 4;
    const int obase = wv * 32;     // 32-col strip per wave (R10-validated)
    const size_t rg0 = (size_t)blockIdx.x * GPB;

    // hoisted per-lane constants: bias + ALL W fragments for this wave's strip
    f32x4 bias4[2];
    #pragma unroll
    for (int i = 0; i < 2; ++i)
        bias4[i] = *(const f32x4*)&bias[obase + i * 16 + hi * 4];

    short8 wfa[4][2], wfx[4][2];   // [m][i], 64 VGPRs, iter/pair-invariant
    #pragma unroll
    for (int m = 0; m < 4; ++m)
        #pragma unroll
        for (int i = 0; i < 2; ++i) {
            const int kk = m * 32 + hi * 8;
            const int o = obase + i * 16 + lo;
            wfa[m][i] = *(const short8*)&Wb[o * KW + kk];          // Wl half
            wfx[m][i] = *(const short8*)&Wb[o * KW + 128 + kk];    // Wr half
        }

    // ---- async DMA of one row-group's raw x (single buffer; wave w only
    // writes/reads its own rows -> cross-wave disjoint, R11/R13-validated)
    auto stage = [&](size_t rg) {
        const float* gp = x + (rg * 16 + r) * CD + c * 4;
        #pragma unroll
        for (int s = 0; s < NNODES; ++s) {
            __builtin_amdgcn_global_load_lds(
                (const __attribute__((address_space(1))) void*)(gp + (size_t)s * (NB * CD)),
                (__attribute__((address_space(3))) void*)&raw[s * 2048 + wv * 256],
                16, 0, 0);
        }
    };

    // ---- convert raw -> bf16 panels in Ad (each wave reads only what it DMA'd)
    auto convert = [&](short* __restrict__ Ad) {
        const int base = r * 128 + c * 4;
        f32x4 v0 = *(const f32x4*)&raw[0 * 2048 + base];
        f32x4 v1 = *(const f32x4*)&raw[1 * 2048 + base];
        f32x4 v2 = *(const f32x4*)&raw[2 * 2048 + base];
        f32x4 v3 = *(const f32x4*)&raw[3 * 2048 + base];
        f32x4 v4 = *(const f32x4*)&raw[4 * 2048 + base];
        f32x4 v5 = *(const f32x4*)&raw[5 * 2048 + base];
        f32x4 S01 = v0 + v1, S25 = v2 + v5, S34 = v3 + v4;
        f32x4 T = S01 + S25 + S34;
        const int k = c * 4;
        *(s16x4*)&Ad[LIDX(0, r, k)] = pack4((T - v0) * 0.2f);      // g0
        *(s16x4*)&Ad[LIDX(1, r, k)] = pack4((T - v1) * 0.2f);      // g1
        *(s16x4*)&Ad[LIDX(2, r, k)] = pack4((S01 + S34) * 0.25f);  // g25
        *(s16x4*)&Ad[LIDX(3, r, k)] = pack4((S01 + S25) * 0.25f);  // g34
        *(s16x4*)&Ad[LIDX(4, r, k)] = pack4(v0);
        *(s16x4*)&Ad[LIDX(5, r, k)] = pack4(v1);
        *(s16x4*)&Ad[LIDX(6, r, k)] = pack4(v2);
        *(s16x4*)&Ad[LIDX(7, r, k)] = pack4(v3);
        *(s16x4*)&Ad[LIDX(8, r, k)] = pack4(v4);
        *(s16x4*)&Ad[LIDX(9, r, k)] = pack4(v5);
    };

    // ---- one node-pair's MFMA (W from hoisted regs; only panel LDS reads)
    auto pairMFMA = [&](const short* __restrict__ Ab, int pa0, int pa1,
                        int px0, int px1, f32x4 acc[2][2]) {
        #pragma unroll
        for (int n = 0; n < 2; ++n)
            #pragma unroll
            for (int i = 0; i < 2; ++i) acc[n][i] = (f32x4){0.f, 0.f, 0.f, 0.f};
        #pragma unroll
        for (int m = 0; m < 4; ++m) {
            const int kk = m * 32 + hi * 8;
            short8 fa0 = *(const short8*)&Ab[LIDX(pa0, lo, kk)];
            short8 fa1 = *(const short8*)&Ab[LIDX(pa1, lo, kk)];
            short8 fx0 = *(const short8*)&Ab[LIDX(px0, lo, kk)];
            short8 fx1 = *(const short8*)&Ab[LIDX(px1, lo, kk)];
            #pragma unroll
            for (int i = 0; i < 2; ++i) {
                acc[0][i] = __builtin_amdgcn_mfma_f32_16x16x32_bf16(wfa[m][i], fa0, acc[0][i], 0, 0, 0);
                acc[1][i] = __builtin_amdgcn_mfma_f32_16x16x32_bf16(wfa[m][i], fa1, acc[1][i], 0, 0, 0);
                acc[0][i] = __builtin_amdgcn_mfma_f32_16x16x32_bf16(wfx[m][i], fx0, acc[0][i], 0, 0, 0);
                acc[1][i] = __builtin_amdgcn_mfma_f32_16x16x32_bf16(wfx[m][i], fx1, acc[1][i], 0, 0, 0);
            }
        }
    };

    // ---- GELU + stores for one node pair
    auto storePair = [&](int n0, int n1, f32x4 acc[2][2], size_t orow) {
        #pragma unroll
        for (int w = 0; w < 2; ++w) {
            const int node = w ? n1 : n0;
            #pragma unroll
            for (int i = 0; i < 2; ++i) {
                const int ocol = obase + i * 16 + hi * 4;
                f32x4 v = acc[w][i] + bias4[i];
                f32x4 g;
                #pragma unroll
                for (int j = 0; j < 4; ++j) {
                    const float s = v[j] * (0.7978845608f + 0.0356774081f * v[j] * v[j]);
                    const float rr = __builtin_amdgcn_exp2f(-2.885390082f * s);
                    g[j] = v[j] * __builtin_amdgcn_rcpf(1.0f + rr);
                }
                *(f32x4*)&out[orow * OUTW + node * 256 + ocol] = g;
            }
        }
    };

    // ---- pipeline prologue: group 0 into A[0]; group 1 DMA in flight
    stage(rg0);
    asm volatile("s_waitcnt vmcnt(0)" ::: "memory");   // per-wave DMA drain
    convert(&A[0][0]);
    if (GPB > 1) stage(rg0 + 1);
    __syncthreads();                                   // publish A[0]

    f32x4 accH[2][2];              // pair (3,4) held across the barrier
    size_t prevRow = 0;

    #pragma unroll 1
    for (int it = 0; it < GPB; ++it) {
        const short* Ab = &A[it & 1][0];
        const size_t orow = (rg0 + it) * 16 + lo;

        // prev group's pair3: full MFMA phase to drain
        if (it) storePair(3, 4, accH, prevRow);

        f32x4 acc[2][2];
        pairMFMA(Ab, 0, 1, 4, 5, acc);   // nodes 0,1 (g0,g1)
        storePair(0, 1, acc, orow);
        pairMFMA(Ab, 2, 2, 6, 9, acc);   // nodes 2,5 (shared g25)
        storePair(2, 5, acc, orow);
        pairMFMA(Ab, 3, 3, 7, 8, accH);  // nodes 3,4 (shared g34) -> held
        prevRow = orow;

        if (it + 1 < GPB) {
            // per-wave wait: group it+1's DMA (issued end of last iter /
            // prologue) + this iter's stores; then convert into other A buf
            asm volatile("s_waitcnt vmcnt(0)" ::: "memory");
            convert(&A[(it + 1) & 1][0]);
            // raw free for this wave (it just read it) -> overwrite w/ it+2
            if (it + 2 < GPB) stage(rg0 + it + 2);
        }
        __syncthreads();                 // publish A[(it+1)&1]
    }
    storePair(3, 4, accH, prevRow);      // final held pair
}

extern "C" void kernel_launch(void* const* d_in, const int* in_sizes, int n_in,
                              void* d_out, int out_size, void* d_ws, size_t ws_size,
                              hipStream_t stream) {
    const float* x  = (const float*)d_in[0];
    const float* Wl = (const float*)d_in[1];
    const float* Wr = (const float*)d_in[2];
    const float* b  = (const float*)d_in[3];
    float* out = (float*)d_out;
    short* Wb = (short*)d_ws;   // 256*256 bf16 = 128 KB

    prep_w<<<dim3(32), dim3(256), 0, stream>>>(Wl, Wr, Wb);
    sage_v13<<<dim3(NBLK), dim3(512), 0, stream>>>(x, Wb, b, out);
}